// Round 1
// baseline (376.020 us; speedup 1.0000x reference)
//
#include <hip/hip_runtime.h>
#include <math.h>

#define PI_F 3.14159265358979323846f

// ---------------- fast device math ----------------
__device__ __forceinline__ float sigm_f(float x) {
    return __fdividef(1.0f, 1.0f + __expf(-x));
}
__device__ __forceinline__ float tanh_f(float x) {
    float xc = fminf(fmaxf(x, -9.0f), 9.0f);
    float e = __expf(2.0f * xc);
    return 1.0f - __fdividef(2.0f, e + 1.0f);
}

// ============================================================
// Kernel 1: 2-layer GRU over reversed action sequence + encoder head.
// 128 threads = 4 samples x 32 hidden-lanes. Weights staged to LDS
// transposed + gate-interleaved: w[input][unit*3 + gate].
// ============================================================
__global__ __launch_bounds__(128)
void gru_kernel(const float* __restrict__ act,
                const float* __restrict__ Wih0, const float* __restrict__ Whh0,
                const float* __restrict__ bih0, const float* __restrict__ bhh0,
                const float* __restrict__ Wih1, const float* __restrict__ Whh1,
                const float* __restrict__ bih1, const float* __restrict__ bhh1,
                const float* __restrict__ encW, const float* __restrict__ encb,
                float* __restrict__ p_out)
{
    __shared__ float wih0_l[6 * 96];
    __shared__ float whh0_l[32 * 96];
    __shared__ float wih1_l[32 * 96];
    __shared__ float whh1_l[32 * 96];
    __shared__ float enc_l[64];
    __shared__ float xbuf[4 * 32 * 6];
    __shared__ float hbuf0[4][32];
    __shared__ float hbuf1[4][32];

    const int tid = threadIdx.x;

    for (int idx = tid; idx < 96 * 6; idx += 128) {
        int r = idx / 6, c = idx - r * 6;
        wih0_l[c * 96 + (r & 31) * 3 + (r >> 5)] = Wih0[idx];
    }
    for (int idx = tid; idx < 96 * 32; idx += 128) {
        int r = idx >> 5, c = idx & 31;
        int d = c * 96 + (r & 31) * 3 + (r >> 5);
        whh0_l[d] = Whh0[idx];
        wih1_l[d] = Wih1[idx];
        whh1_l[d] = Whh1[idx];
    }
    if (tid < 64) {
        int o = tid >> 5, j = tid & 31;
        enc_l[j * 2 + o] = encW[o * 32 + j];
    }
    {
        const float inv3 = (1.0f / 3.0f);
        int base = blockIdx.x * (4 * 32 * 6);
        for (int idx = tid; idx < 4 * 32 * 6; idx += 128)
            xbuf[idx] = act[base + idx] * inv3;
    }
    __syncthreads();

    const int s = tid >> 5;   // sample within block
    const int j = tid & 31;   // hidden unit
    const int b = blockIdx.x * 4 + s;
    const int j3 = j * 3;

    const float bi0r = bih0[j], bi0z = bih0[32 + j], bi0n = bih0[64 + j];
    const float bh0r = bhh0[j], bh0z = bhh0[32 + j], bh0n = bhh0[64 + j];
    const float bi1r = bih1[j], bi1z = bih1[32 + j], bi1n = bih1[64 + j];
    const float bh1r = bhh1[j], bh1z = bhh1[32 + j], bh1n = bhh1[64 + j];

    float* hb0 = &hbuf0[s][0];
    float* hb1 = &hbuf1[s][0];
    hb0[j] = 0.0f;
    hb1[j] = 0.0f;
    float h0 = 0.0f, h1 = 0.0f;
    const float* xs = &xbuf[s * 192];

    for (int t = 0; t < 32; ++t) {
        const float* xt = &xs[(31 - t) * 6];  // time-reversed input

        // ---- layer 0 ----
        float ar = bi0r, az = bi0z, an = bi0n;
        #pragma unroll
        for (int d = 0; d < 6; ++d) {
            float xv = xt[d];
            const float* w = &wih0_l[d * 96 + j3];
            ar = fmaf(xv, w[0], ar); az = fmaf(xv, w[1], az); an = fmaf(xv, w[2], an);
        }
        float gr = bh0r, gz = bh0z, gn = bh0n;
        #pragma unroll
        for (int i = 0; i < 32; ++i) {
            float hi = hb0[i];
            const float* w = &whh0_l[i * 96 + j3];
            gr = fmaf(hi, w[0], gr); gz = fmaf(hi, w[1], gz); gn = fmaf(hi, w[2], gn);
        }
        float r = sigm_f(ar + gr);
        float z = sigm_f(az + gz);
        float n = tanh_f(an + r * gn);
        h0 = (1.0f - z) * n + z * h0;
        hb0[j] = h0;

        // ---- layer 1 (input = new h0) ----
        float a1r = bi1r, a1z = bi1z, a1n = bi1n;
        #pragma unroll
        for (int i = 0; i < 32; ++i) {
            float hi = hb0[i];
            const float* w = &wih1_l[i * 96 + j3];
            a1r = fmaf(hi, w[0], a1r); a1z = fmaf(hi, w[1], a1z); a1n = fmaf(hi, w[2], a1n);
        }
        float g1r = bh1r, g1z = bh1z, g1n = bh1n;
        #pragma unroll
        for (int i = 0; i < 32; ++i) {
            float hi = hb1[i];
            const float* w = &whh1_l[i * 96 + j3];
            g1r = fmaf(hi, w[0], g1r); g1z = fmaf(hi, w[1], g1z); g1n = fmaf(hi, w[2], g1n);
        }
        float r1 = sigm_f(a1r + g1r);
        float z1 = sigm_f(a1z + g1z);
        float n1 = tanh_f(a1n + r1 * g1n);
        h1 = (1.0f - z1) * n1 + z1 * h1;
        hb1[j] = h1;
    }

    // encoder head: p_action[b][o] = sum_j h1_j * encW[o][j] + encb[o]
    float v0 = h1 * enc_l[j * 2 + 0];
    float v1 = h1 * enc_l[j * 2 + 1];
    #pragma unroll
    for (int off = 16; off > 0; off >>= 1) {
        v0 += __shfl_xor(v0, off, 32);
        v1 += __shfl_xor(v1, off, 32);
    }
    if (j == 0) {
        p_out[b * 2 + 0] = v0 + encb[0];
        p_out[b * 2 + 1] = v1 + encb[1];
    }
}

// ============================================================
// Kernel 2: per-(b,t) MLP + Laplace series.
// 256 threads = 4 waves; lane = item (64 items/block), wave w owns
// the k-class k ≡ w (mod 4). Weights are wave-uniform -> s_load.
// ang = pi*k*(t/Tc) = pi*k/2 exactly => only Fr (even k) / Fi (odd k).
// ============================================================
__global__ __launch_bounds__(256)
void mlp_kernel(const float* __restrict__ obs, const float* __restrict__ ts,
                const float* __restrict__ p_act,
                const float* __restrict__ W1, const float* __restrict__ b1,
                const float* __restrict__ W2, const float* __restrict__ b2,
                const float* __restrict__ W3, const float* __restrict__ b3,
                float* __restrict__ out)
{
    __shared__ float h1_lds[64 * 64];
    __shared__ float h2_lds[64 * 64];
    __shared__ float f_lds[4 * 64 * 17];
    __shared__ float scale_lds[64];

    const int tid = threadIdx.x;
    const int w = tid >> 6;     // wave id = k-class
    const int l = tid & 63;     // item lane
    const int item = blockIdx.x * 64 + l;
    const int b = item >> 4;

    const float t = ts[item];
    const float Tc = 2.0f * t;
    const float rTc = __fdividef(1.0f, Tc);
    const float gamma = 0.001f + 4.6051701859880913680f * rTc;  // -ln(0.01)/Tc

    // ---- build inp[85] = [theta_s(33), phi_s(33), p(19)] ----
    float inp[85];
    const float g2 = gamma * gamma;
    const float rg = __fdividef(1.0f, gamma);
    #pragma unroll
    for (int k = 0; k < 33; ++k) {
        float sim = (PI_F * (float)k) * rTc;
        inp[k] = atanf(sim * rg);                        // atan2(s_im, s_re>0)
        float sq = fmaf(sim, sim, g2);
        inp[33 + k] = asinf(__fdividef(sq - 1.0f, sq + 1.0f));
    }
    #pragma unroll
    for (int i = 0; i < 17; ++i) inp[66 + i] = obs[b * 17 + i];
    inp[83] = p_act[b * 2 + 0];
    inp[84] = p_act[b * 2 + 1];

    // ---- H1 (each wave computes 16 of 64 outputs) ----
    {
        const int obase = w * 16;
        for (int oo = 0; oo < 16; ++oo) {
            const int o = obase + oo;
            const float* wr = &W1[o * 85];
            float acc = b1[o];
            #pragma unroll
            for (int i = 0; i < 85; ++i) acc = fmaf(inp[i], wr[i], acc);
            h1_lds[o * 64 + l] = tanh_f(acc);
        }
    }
    __syncthreads();
    float h1r[64];
    #pragma unroll
    for (int i = 0; i < 64; ++i) h1r[i] = h1_lds[i * 64 + l];

    // ---- H2 ----
    {
        const int obase = w * 16;
        for (int oo = 0; oo < 16; ++oo) {
            const int o = obase + oo;
            const float* wr = &W2[o * 64];
            float acc = b2[o];
            #pragma unroll
            for (int i = 0; i < 64; ++i) acc = fmaf(h1r[i], wr[i], acc);
            h2_lds[o * 64 + l] = tanh_f(acc);
        }
    }
    __syncthreads();
    float h2r[64];
    #pragma unroll
    for (int i = 0; i < 64; ++i) h2r[i] = h2_lds[i * 64 + l];

    if (w == 3) scale_lds[l] = __expf(gamma * t) * rTc;

    // ---- W3 + series epilogue for k ≡ w (mod 4) ----
    // k%4==0: +Fr (0.5 at k=0); k%4==1: -Fi; k%4==2: -Fr; k%4==3: +Fi
    const float csgn = (w == 1 || w == 2) ? -1.0f : 1.0f;
    for (int o = 0; o < 17; ++o) {
        float facc = 0.0f;
        for (int k = w; k < 33; k += 4) {
            const int rt = o * 33 + k;          // theta row
            const float* wt = &W3[rt * 64];
            const float* wp = &W3[(rt + 561) * 64];  // phi row = (o+17)*33+k
            float at = b3[rt], ap = b3[rt + 561];
            #pragma unroll
            for (int i = 0; i < 64; ++i) {
                at = fmaf(h2r[i], wt[i], at);
                ap = fmaf(h2r[i], wp[i], ap);
            }
            float theta = tanh_f(at) * PI_F;
            float phi   = tanh_f(ap) * (0.5f * PI_F);
            float sph = __sinf(phi), cph = __cosf(phi);
            float rd = __fdividef(1.0f, 1.0f - sph);
            float tr = (w == 0 || w == 2) ? __cosf(theta) : __sinf(theta);
            float wk = (k == 0) ? 0.5f : 1.0f;
            facc = fmaf(csgn * wk, tr * cph * rd, facc);
        }
        f_lds[(w * 64 + l) * 17 + o] = facc;
    }
    __syncthreads();

    // ---- reduce 4 k-class partials, scale, write out ----
    const int base_item = blockIdx.x * 64;
    for (int idx = tid; idx < 64 * 17; idx += 256) {
        const int li = idx / 17;
        const int o  = idx - li * 17;
        float tot = f_lds[li * 17 + o] + f_lds[(64 + li) * 17 + o]
                  + f_lds[(128 + li) * 17 + o] + f_lds[(192 + li) * 17 + o];
        out[(base_item + li) * 17 + o] = tot * scale_lds[li];
    }
}

extern "C" void kernel_launch(void* const* d_in, const int* in_sizes, int n_in,
                              void* d_out, int out_size, void* d_ws, size_t ws_size,
                              hipStream_t stream) {
    (void)in_sizes; (void)n_in; (void)out_size; (void)ws_size;
    const float* obs  = (const float*)d_in[0];
    const float* act  = (const float*)d_in[1];
    const float* ts   = (const float*)d_in[2];
    const float* Wih0 = (const float*)d_in[3];
    const float* Whh0 = (const float*)d_in[4];
    const float* bih0 = (const float*)d_in[5];
    const float* bhh0 = (const float*)d_in[6];
    const float* Wih1 = (const float*)d_in[7];
    const float* Whh1 = (const float*)d_in[8];
    const float* bih1 = (const float*)d_in[9];
    const float* bhh1 = (const float*)d_in[10];
    const float* encW = (const float*)d_in[11];
    const float* encb = (const float*)d_in[12];
    const float* W1   = (const float*)d_in[13];
    const float* b1   = (const float*)d_in[14];
    const float* W2   = (const float*)d_in[15];
    const float* b2   = (const float*)d_in[16];
    const float* W3   = (const float*)d_in[17];
    const float* b3   = (const float*)d_in[18];
    float* o_ptr  = (float*)d_out;
    float* p_act  = (float*)d_ws;   // 2048*2 floats scratch

    gru_kernel<<<dim3(512), dim3(128), 0, stream>>>(
        act, Wih0, Whh0, bih0, bhh0, Wih1, Whh1, bih1, bhh1, encW, encb, p_act);
    mlp_kernel<<<dim3(512), dim3(256), 0, stream>>>(
        obs, ts, p_act, W1, b1, W2, b2, W3, b3, o_ptr);
}